// Round 2
// baseline (315.337 us; speedup 1.0000x reference)
//
#include <hip/hip_runtime.h>

#define IMG_H   128
#define NPIX    (IMG_H * IMG_H)     // 16384
#define TPB     512
#define VITERS  (NPIX / (TPB * 4))  // 8 float4 iterations per thread
#define NWAVES  (TPB / 64)          // 8

// fast atan2, max err ~1e-4 rad (minimax on [0,1] + quadrant fixup)
__device__ __forceinline__ float fast_atan2f(float y, float x) {
    float ax = fabsf(x), ay = fabsf(y);
    float mx = fmaxf(fmaxf(ax, ay), 1e-30f);
    float mn = fminf(ax, ay);
    float a  = mn * __builtin_amdgcn_rcpf(mx);
    float t  = a * a;
    float r  = fmaf(t, fmaf(t, fmaf(t, fmaf(t, 0.0208351f, -0.0851330f),
                                    0.1801410f), -0.3302995f), 0.9998660f);
    r = a * r;
    if (ay > ax)  r = 1.5707963268f - r;
    if (x < 0.0f) r = 3.1415926536f - r;
    return copysignf(r, y);
}

__global__ __launch_bounds__(TPB)
void decode_kernel(const float* __restrict__ W,
                   const float* __restrict__ ng,
                   const float* __restrict__ nu,
                   float* __restrict__ out)
{
    const int b   = blockIdx.x;
    const int tid = threadIdx.x;
    const float* Wb = W + (size_t)b * 16;

    const float w0  = Wb[0],  w1  = Wb[1],  w2  = Wb[2],  w3  = Wb[3];
    const float w4  = Wb[4],  w5  = Wb[5],  w6  = Wb[6],  w7  = Wb[7];
    const float w8  = Wb[8],  w9  = Wb[9],  w10 = Wb[10], w11 = Wb[11];
    const float w12 = Wb[12], w13 = Wb[13], w14 = Wb[14], w15 = Wb[15];

    const float PI    = 3.14159265358979323846f;
    const float PI128 = PI / 128.0f;

    // per-image derived constants
    const float cdisk = w0 * 6.0f;
    const float half  = floorf(fminf(fmaxf(fabsf(w1) * 8.0f + 2.0f, 2.0f), 12.0f));
    const float lo    = 64.0f - half, hi = 64.0f + half;
    const float s2    = w2 * (PI / 64.0f);            // w2*2pi/128
    const float s3    = w3 * (PI / 64.0f);
    const float s4    = w4 * (PI / 256.0f);           // w4*pi*((i+j)/2)/128
    const float c5    = w5 * 10.0f * PI128;           // (fj + w5*10)*pi/128
    const float off7  = truncf(w7 * 5.0f);
    const float bxy   = 64.0f + off7;
    const float sig   = 4.0f + fabsf(w7) * 5.0f;
    const float nb    = -1.0f / (2.0f * sig * sig);   // precise divide
    const float r8    = w8 * 10.0f;
    const float cbs   = floorf(fminf(fmaxf(fabsf(w9) * 8.0f + 2.0f, 2.0f), 16.0f));
    const float icbs  = 1.0f / cbs;                   // precise divide (per-image)
    // precise sin/cos for the rotated-line threshold constants
    const float ca    = cosf(w10 * PI);
    const float sa    = sinf(w10 * PI);
    const float a11   = w11 * 4.0f;
    const float n12   = 0.2f * w12;
    const float n13   = 0.2f * w13;
    const float con2  = (w15 > 0.0f) ? -(1.0f + w14) : (1.0f + w14);

    const float4* ng4  = (const float4*)(ng  + (size_t)b * NPIX);
    const float4* nu4  = (const float4*)(nu  + (size_t)b * NPIX);
    float4*       out4 = (float4*)(out + (size_t)b * NPIX);

    float4 vals[VITERS];
    float vmin =  3.402823466e38f;
    float vmax = -3.402823466e38f;

    #pragma unroll
    for (int k = 0; k < VITERS; ++k) {
        const int p4 = k * TPB + tid;        // float4 index
        const int p  = p4 * 4;
        const int i  = p >> 7;
        const int j0 = p & 127;
        const float fi = (float)i;

        const float4 g = ng4[p4];
        const float4 u = nu4[p4];
        const float gg[4] = {g.x, g.y, g.z, g.w};
        const float uu[4] = {u.x, u.y, u.z, u.w};

        // row-constant pieces (shared by the 4 pixels of this float4)
        const float dx     = fi - 64.0f;
        const float rowsin = 0.5f * __sinf(s2 * fi);
        const bool  mi     = (fi >= lo) && (fi < hi);
        // +0.25 bias makes floor exact despite reciprocal rounding:
        // fi,cbs are small ints; margin to integer boundary >= 0.25/16 >> mul err
        const float ci     = floorf((fi + 0.25f) * icbs);
        const float dxb    = fi - bxy;
        const float dxb2   = dxb * dxb;

        float vout[4];
        #pragma unroll
        for (int q = 0; q < 4; ++q) {
            const float fj = (float)(j0 + q);
            const float dy = fj - 64.0f;
            const float r2 = fmaf(dx, dx, dy * dy);   // exact (integers < 2^24)
            const float r  = sqrtf(r2);               // correctly rounded: bit-exact vs np

            // disk
            float v = fminf(fmaxf(cdisk - r, 0.0f), 1.0f);
            // central square
            if (mi && (fj >= lo) && (fj < hi)) v += 0.5f;
            // sinusoids
            v += rowsin;
            v += 0.5f * __sinf(s3 * fj);
            v += 0.5f * __sinf(s4 * (fi + fj));
            v += 0.5f * __sinf(fmaf(fj, PI128, c5));
            // brightness
            v += w6;
            // gaussian blob
            const float dyb = fj - bxy;
            v += __expf(nb * fmaf(dyb, dyb, dxb2));
            // ring (bit-exact: exact r2, correctly-rounded sqrt, same fp32 ops as np)
            const float tr = r - r8;
            if (tr * tr < 10.0f) v += 1.0f;
            // checkerboard (exact floor via +0.25 bias)
            const float cj = floorf((fj + 0.25f) * icbs);
            if (((int)(ci + cj)) & 1) v += 0.3f;
            // rotated line
            const float rot = ca * dx + sa * dy;
            if (fabsf(rot) < 3.0f) v += 0.6f;
            // angular sinusoid
            const float theta = fast_atan2f(dy, dx);
            v += 0.5f * __sinf(theta * a11);
            // noise
            v = fmaf(gg[q], n12, v);
            v = fmaf(uu[q] - 0.5f, n13, v);
            // contrast (+ optional inversion folded into con2)
            v = fmaf(v - 0.5f, con2, 0.5f);

            vout[q] = v;
            vmin = fminf(vmin, v);
            vmax = fmaxf(vmax, v);
        }
        vals[k] = make_float4(vout[0], vout[1], vout[2], vout[3]);
    }

    // wave-level butterfly reduction (64 lanes)
    #pragma unroll
    for (int off = 32; off > 0; off >>= 1) {
        vmin = fminf(vmin, __shfl_xor(vmin, off, 64));
        vmax = fmaxf(vmax, __shfl_xor(vmax, off, 64));
    }

    __shared__ float smin[NWAVES], smax[NWAVES];
    const int wave = tid >> 6;
    if ((tid & 63) == 0) { smin[wave] = vmin; smax[wave] = vmax; }
    __syncthreads();
    float bmin = smin[0], bmax = smax[0];
    #pragma unroll
    for (int wv = 1; wv < NWAVES; ++wv) {
        bmin = fminf(bmin, smin[wv]);
        bmax = fmaxf(bmax, smax[wv]);
    }

    const float scale = 1.0f / (bmax - bmin + 1e-8f);

    #pragma unroll
    for (int k = 0; k < VITERS; ++k) {
        const int p4 = k * TPB + tid;
        float4 v = vals[k];
        v.x = (v.x - bmin) * scale;
        v.y = (v.y - bmin) * scale;
        v.z = (v.z - bmin) * scale;
        v.w = (v.w - bmin) * scale;
        out4[p4] = v;
    }
}

extern "C" void kernel_launch(void* const* d_in, const int* in_sizes, int n_in,
                              void* d_out, int out_size, void* d_ws, size_t ws_size,
                              hipStream_t stream) {
    const float* W  = (const float*)d_in[0];
    const float* ng = (const float*)d_in[1];
    const float* nu = (const float*)d_in[2];
    float* out = (float*)d_out;
    const int B = in_sizes[0] / 16;   // 2048
    decode_kernel<<<dim3(B), dim3(TPB), 0, stream>>>(W, ng, nu, out);
}